// Round 2
// baseline (1144.765 us; speedup 1.0000x reference)
//
#include <hip/hip_runtime.h>
#include <math.h>

#define T_NTIME  2048
#define T_NBATCH 128
#define T_INSIZE 512
#define T_SIZE   16
#define T_NROWS  (T_NTIME * T_NBATCH)
#define TILES_PER_BLOCK 8

__device__ __forceinline__ float sp_f(float v) {
  return fmaxf(v, 0.0f) + log1pf(__expf(-fabsf(v)));
}
__device__ __forceinline__ float tanh5_f(float v) {
  float a = fabsf(v);
  float e = __expf(-2.0f * a);
  float t = (1.0f - e) / (1.0f + e);
  return copysignf(5.0f * t, v);
}
__device__ __forceinline__ float lae_f(float a, float c) {
  float m = fmaxf(a, c);
  return m + log1pf(__expf(-fabsf(a - c)));
}

// ---------- K1: y = x @ W^T + b, activations; trans written pre-logZ ----------
// Wave = 8 rows x 8 col-groups. Lane (sub,g): row = base+sub, cols {k*32+g*4..+3}.
// Loads coalesced (8 lanes cover one 128B line), depth-2 register prefetch,
// 8-lane xor-tree reduction, lane g emits channels {2g, 2g+1}.
__global__ __launch_bounds__(256, 4)
void k_gemm_act(const float* __restrict__ x, const float* __restrict__ W,
                const float* __restrict__ bias, float* __restrict__ out) {
  __shared__ float wl[T_SIZE * T_INSIZE];  // 32 KB
  const int tid = threadIdx.x;
  {
    const float4* src = (const float4*)W;
    float4* dst = (float4*)wl;
#pragma unroll
    for (int k = 0; k < (T_SIZE * T_INSIZE / 4) / 256; ++k)
      dst[tid + k * 256] = src[tid + k * 256];
  }
  const int g = tid & 7;                 // column-group
  const int sub = (tid & 63) >> 3;       // row-in-wave 0..7
  const int wave = tid >> 6;             // 0..3
  const int s0 = g * 2;                  // this lane's output channels
  const float b0 = bias[s0], b1 = bias[s0 + 1];
  __syncthreads();

  const int coff = g * 4;
  long row = (long)blockIdx.x * (TILES_PER_BLOCK * 32) + wave * 8 + sub;
  const float* xp = x + row * T_INSIZE + coff;

  float4 cur = *(const float4*)(xp);        // k=0
  float4 nx1 = *(const float4*)(xp + 32);   // k=1

  for (int t = 0; t < TILES_PER_BLOCK; ++t) {
    float acc[T_SIZE];
#pragma unroll
    for (int s = 0; s < T_SIZE; ++s) acc[s] = 0.0f;

#pragma unroll
    for (int k = 0; k < 16; ++k) {
      const float* pa;
      if (k < 14) pa = xp + (k + 2) * 32;                              // this tile k+2
      else if (t + 1 < TILES_PER_BLOCK) pa = xp + 32 * T_INSIZE + (k - 14) * 32;  // next tile k0/k1
      else pa = xp;                                                    // clamp (discarded)
      const float4 nx2 = *(const float4*)pa;
#pragma unroll
      for (int s = 0; s < T_SIZE; ++s) {
        const float4 w4 = *(const float4*)(wl + s * T_INSIZE + k * 32 + coff);
        acc[s] = fmaf(cur.x, w4.x, acc[s]);
        acc[s] = fmaf(cur.y, w4.y, acc[s]);
        acc[s] = fmaf(cur.z, w4.z, acc[s]);
        acc[s] = fmaf(cur.w, w4.w, acc[s]);
      }
      cur = nx1;
      nx1 = nx2;
    }

#pragma unroll
    for (int s = 0; s < T_SIZE; ++s) {
      acc[s] += __shfl_xor(acc[s], 1);
      acc[s] += __shfl_xor(acc[s], 2);
      acc[s] += __shfl_xor(acc[s], 4);
    }
    const float y0 = acc[s0] + b0;
    const float y1 = acc[s0 + 1] + b1;
    float2 o;
    o.x = (s0 < 8) ? ((s0 < 4 ? 1.0f : 0.1f) + sp_f(y0)) : tanh5_f(y0);
    o.y = (s0 + 1 < 8) ? ((s0 + 1 < 4 ? 1.0f : 0.1f) + sp_f(y1)) : tanh5_f(y1);
    *(float2*)(out + row * T_SIZE + s0) = o;

    row += 32;
    xp += 32 * T_INSIZE;
  }
}

// ---------- K2a: per-(b, chunk, basis-col) chunk transfer-matrix columns ----------
__global__ void k_scan_chunks(const float* __restrict__ out, float* __restrict__ mats,
                              int nchunks) {
  const int gtid = blockIdx.x * blockDim.x + threadIdx.x;
  const int colslot = gtid & 7;
  const int b = (gtid >> 3) & (T_NBATCH - 1);
  const int chunk = gtid >> 10;
  if (chunk >= nchunks) return;
  if (colslot >= 5) return;

  const int steps = T_NTIME / nchunks;
  const int t0 = chunk * steps;
  const float NEG = -1e30f;
  float f0 = (colslot == 0) ? 0.0f : NEG;
  float f1 = (colslot == 1) ? 0.0f : NEG;
  float f2 = (colslot == 2) ? 0.0f : NEG;
  float f3 = (colslot == 3) ? 0.0f : NEG;
  const float t4 = (colslot == 4) ? 0.0f : NEG;

  const long stride = T_NBATCH * T_SIZE;
  const float* p = out + ((long)t0 * T_NBATCH + b) * T_SIZE + 8;
  float4 mv = *(const float4*)(p);
  float4 st = *(const float4*)(p + 4);
  for (int s = 0; s < steps; ++s) {
    const float* pn = (s + 1 < steps) ? p + stride : p;
    const float4 mvn = *(const float4*)(pn);
    const float4 stn = *(const float4*)(pn + 4);

    float m, ss0, ss1, ss2, ss3;
    m = fmaxf(fmaxf(f1, f2), fmaxf(f3, t4));
    ss0 = m + __logf(__expf(f1 - m) + __expf(f2 - m) + __expf(f3 - m) + __expf(t4 - m));
    m = fmaxf(fmaxf(f0, f2), fmaxf(f3, t4));
    ss1 = m + __logf(__expf(f0 - m) + __expf(f2 - m) + __expf(f3 - m) + __expf(t4 - m));
    m = fmaxf(fmaxf(f0, f1), fmaxf(f3, t4));
    ss2 = m + __logf(__expf(f0 - m) + __expf(f1 - m) + __expf(f3 - m) + __expf(t4 - m));
    m = fmaxf(fmaxf(f0, f1), fmaxf(f2, t4));
    ss3 = m + __logf(__expf(f0 - m) + __expf(f1 - m) + __expf(f2 - m) + __expf(t4 - m));

    const float n0 = lae_f(f0 + st.x, ss0 + mv.x);
    const float n1 = lae_f(f1 + st.y, ss1 + mv.y);
    const float n2 = lae_f(f2 + st.z, ss2 + mv.z);
    const float n3 = lae_f(f3 + st.w, ss3 + mv.w);
    f0 = n0; f1 = n1; f2 = n2; f3 = n3;
    mv = mvn; st = stn; p = pn;
  }
  float* d = mats + (((long)chunk * T_NBATCH + b) * 5 + colslot) * 4;
  d[0] = f0; d[1] = f1; d[2] = f2; d[3] = f3;
}

// ---------- K2b: serial combine of chunk matrices per batch; logZ/T out ----------
__global__ void k_combine(const float* __restrict__ mats, float* __restrict__ logz,
                          int nchunks) {
  const int tid = threadIdx.x;       // 0..511
  const int i = tid & 3;             // state row
  const int b = tid >> 2;            // batch
  if (b >= T_NBATCH) return;
  float v = 0.0f;                    // v[i]; implicit v[4] = 0 constant
  for (int c = 0; c < nchunks; ++c) {
    const float* T = mats + ((long)c * T_NBATCH + b) * 20;  // T[col*4 + row]
    const float vx1 = __shfl_xor(v, 1);
    const float vx2 = __shfl_xor(v, 2);
    const float vx3 = __shfl_xor(v, 3);
    const float a0 = T[i * 4 + i] + v;
    const float a1 = T[(i ^ 1) * 4 + i] + vx1;
    const float a2 = T[(i ^ 2) * 4 + i] + vx2;
    const float a3 = T[(i ^ 3) * 4 + i] + vx3;
    const float a4 = T[16 + i];
    float m = fmaxf(fmaxf(a0, a1), fmaxf(fmaxf(a2, a3), a4));
    v = m + __logf(__expf(a0 - m) + __expf(a1 - m) + __expf(a2 - m) +
                   __expf(a3 - m) + __expf(a4 - m));
  }
  float m1 = fmaxf(v, __shfl_xor(v, 1));
  m1 = fmaxf(m1, __shfl_xor(m1, 2));
  float e = __expf(v - m1);
  e += __shfl_xor(e, 1);
  e += __shfl_xor(e, 2);
  const float lz = m1 + __logf(e);
  if (i == 0) logz[b] = lz * (1.0f / (float)T_NTIME);
}

// ---------- K3: out[t][b][8..15] -= logZ[b]/T ----------
__global__ void k_sub(float* __restrict__ out, const float* __restrict__ logz) {
  const long n = (long)blockIdx.x * blockDim.x + threadIdx.x;
  if (n >= (long)T_NROWS * 2) return;
  const long tb = n >> 1;
  const int b = (int)(tb & (T_NBATCH - 1));
  const float lz = logz[b];
  float4* p = (float4*)(out + tb * T_SIZE + 8 + (n & 1) * 4);
  float4 v = *p;
  v.x -= lz; v.y -= lz; v.z -= lz; v.w -= lz;
  *p = v;
}

extern "C" void kernel_launch(void* const* d_in, const int* in_sizes, int n_in,
                              void* d_out, int out_size, void* d_ws, size_t ws_size,
                              hipStream_t stream) {
  const float* x    = (const float*)d_in[0];
  const float* W    = (const float*)d_in[1];
  const float* bias = (const float*)d_in[2];
  float* out = (float*)d_out;
  float* ws  = (float*)d_ws;

  int C = 64;
  while (C > 1 && (size_t)((long)C * T_NBATCH * 20 + T_NBATCH) * 4 > ws_size) C >>= 1;
  float* mats = ws;
  float* logz = ws + (long)C * T_NBATCH * 20;

  k_gemm_act<<<T_NROWS / 256, 256, 0, stream>>>(x, W, bias, out);

  const int thr2 = C * T_NBATCH * 8;
  k_scan_chunks<<<thr2 / 256, 256, 0, stream>>>(out, mats, C);
  k_combine<<<1, 512, 0, stream>>>(mats, logz, C);
  k_sub<<<(T_NROWS * 2) / 256, 256, 0, stream>>>(out, logz);
}

// Round 3
// 408.859 us; speedup vs baseline: 2.7999x; 2.7999x over previous
//
#include <hip/hip_runtime.h>
#include <math.h>

#define T_NTIME  2048
#define T_NBATCH 128
#define T_INSIZE 512
#define T_SIZE   16
#define T_NROWS  (T_NTIME * T_NBATCH)
#define MAT_STRIDE 24   // padded per-(chunk,b) transfer-matrix stride (floats), 16B-aligned

__device__ __forceinline__ float sp_f(float v) {
  return fmaxf(v, 0.0f) + log1pf(__expf(-fabsf(v)));
}
__device__ __forceinline__ float tanh5_f(float v) {
  float a = fabsf(v);
  float e = __expf(-2.0f * a);
  float t = (1.0f - e) / (1.0f + e);
  return copysignf(5.0f * t, v);
}
__device__ __forceinline__ float lae_f(float a, float c) {
  float m = fmaxf(a, c);
  return m + log1pf(__expf(-fabsf(a - c)));
}

// ---------- K1: y = x @ W^T + b, activations; trans written pre-logZ ----------
// One row per thread. Row read in 16 groups of 128B (8 x float4), ping-pong
// register prefetch so every cache line is fetched+fully consumed by its own
// group (no amplification, ~8 loads in flight). W broadcast from LDS.
__global__ __launch_bounds__(256, 4)
void k_gemm_act(const float* __restrict__ x, const float* __restrict__ W,
                const float* __restrict__ bias, float* __restrict__ out) {
  __shared__ float wl[T_SIZE * T_INSIZE];  // 32 KB
  const int tid = threadIdx.x;
  {
    const float4* src = (const float4*)W;
    float4* dst = (float4*)wl;
#pragma unroll
    for (int k = 0; k < 8; ++k) dst[tid + k * 256] = src[tid + k * 256];
  }
  __syncthreads();

  const long row = (long)blockIdx.x * 256 + tid;
  const float* __restrict__ xp = x + row * T_INSIZE;

  float acc[T_SIZE];
#pragma unroll
  for (int s = 0; s < T_SIZE; ++s) acc[s] = 0.0f;

  float4 cur[8], nxt[8];
#pragma unroll
  for (int j = 0; j < 8; ++j) cur[j] = *(const float4*)(xp + j * 4);

#define COMPUTE_GROUP(buf, gg)                                              \
  do {                                                                      \
    _Pragma("unroll")                                                       \
    for (int j = 0; j < 8; ++j) {                                           \
      const float4 xv = buf[j];                                             \
      _Pragma("unroll")                                                     \
      for (int s = 0; s < T_SIZE; ++s) {                                    \
        const float4 w4 = *(const float4*)(wl + s * T_INSIZE + (gg) * 32 + j * 4); \
        acc[s] = fmaf(xv.x, w4.x, acc[s]);                                  \
        acc[s] = fmaf(xv.y, w4.y, acc[s]);                                  \
        acc[s] = fmaf(xv.z, w4.z, acc[s]);                                  \
        acc[s] = fmaf(xv.w, w4.w, acc[s]);                                  \
      }                                                                     \
    }                                                                       \
  } while (0)

#pragma unroll 1
  for (int g = 0; g < 16; g += 2) {
    // prefetch group g+1
#pragma unroll
    for (int j = 0; j < 8; ++j) nxt[j] = *(const float4*)(xp + (g + 1) * 32 + j * 4);
    COMPUTE_GROUP(cur, g);
    if (g + 2 < 16) {
#pragma unroll
      for (int j = 0; j < 8; ++j) cur[j] = *(const float4*)(xp + (g + 2) * 32 + j * 4);
    }
    COMPUTE_GROUP(nxt, g + 1);
  }
#undef COMPUTE_GROUP

  float* op = out + row * T_SIZE;
  float4 v;
  v.x = 1.0f + sp_f(acc[0] + bias[0]);
  v.y = 1.0f + sp_f(acc[1] + bias[1]);
  v.z = 1.0f + sp_f(acc[2] + bias[2]);
  v.w = 1.0f + sp_f(acc[3] + bias[3]);
  *(float4*)(op + 0) = v;
  v.x = 0.1f + sp_f(acc[4] + bias[4]);
  v.y = 0.1f + sp_f(acc[5] + bias[5]);
  v.z = 0.1f + sp_f(acc[6] + bias[6]);
  v.w = 0.1f + sp_f(acc[7] + bias[7]);
  *(float4*)(op + 4) = v;
  v.x = tanh5_f(acc[8] + bias[8]);
  v.y = tanh5_f(acc[9] + bias[9]);
  v.z = tanh5_f(acc[10] + bias[10]);
  v.w = tanh5_f(acc[11] + bias[11]);
  *(float4*)(op + 8) = v;
  v.x = tanh5_f(acc[12] + bias[12]);
  v.y = tanh5_f(acc[13] + bias[13]);
  v.z = tanh5_f(acc[14] + bias[14]);
  v.w = tanh5_f(acc[15] + bias[15]);
  *(float4*)(op + 12) = v;
}

// ---------- K2a: per-(b, chunk, basis-col) chunk transfer-matrix columns ----------
__global__ void k_scan_chunks(const float* __restrict__ out, float* __restrict__ mats,
                              int nchunks) {
  const int gtid = blockIdx.x * blockDim.x + threadIdx.x;
  const int colslot = gtid & 7;
  const int b = (gtid >> 3) & (T_NBATCH - 1);
  const int chunk = gtid >> 10;
  if (chunk >= nchunks) return;
  if (colslot >= 5) return;

  const int steps = T_NTIME / nchunks;
  const int t0 = chunk * steps;
  const float NEG = -1e30f;
  float f0 = (colslot == 0) ? 0.0f : NEG;
  float f1 = (colslot == 1) ? 0.0f : NEG;
  float f2 = (colslot == 2) ? 0.0f : NEG;
  float f3 = (colslot == 3) ? 0.0f : NEG;
  const float t4 = (colslot == 4) ? 0.0f : NEG;

  const long stride = T_NBATCH * T_SIZE;
  const float* p = out + ((long)t0 * T_NBATCH + b) * T_SIZE + 8;
  float4 mv = *(const float4*)(p);
  float4 st = *(const float4*)(p + 4);
  for (int s = 0; s < steps; ++s) {
    const float* pn = (s + 1 < steps) ? p + stride : p;
    const float4 mvn = *(const float4*)(pn);
    const float4 stn = *(const float4*)(pn + 4);

    float m, ss0, ss1, ss2, ss3;
    m = fmaxf(fmaxf(f1, f2), fmaxf(f3, t4));
    ss0 = m + __logf(__expf(f1 - m) + __expf(f2 - m) + __expf(f3 - m) + __expf(t4 - m));
    m = fmaxf(fmaxf(f0, f2), fmaxf(f3, t4));
    ss1 = m + __logf(__expf(f0 - m) + __expf(f2 - m) + __expf(f3 - m) + __expf(t4 - m));
    m = fmaxf(fmaxf(f0, f1), fmaxf(f3, t4));
    ss2 = m + __logf(__expf(f0 - m) + __expf(f1 - m) + __expf(f3 - m) + __expf(t4 - m));
    m = fmaxf(fmaxf(f0, f1), fmaxf(f2, t4));
    ss3 = m + __logf(__expf(f0 - m) + __expf(f1 - m) + __expf(f2 - m) + __expf(t4 - m));

    const float n0 = lae_f(f0 + st.x, ss0 + mv.x);
    const float n1 = lae_f(f1 + st.y, ss1 + mv.y);
    const float n2 = lae_f(f2 + st.z, ss2 + mv.z);
    const float n3 = lae_f(f3 + st.w, ss3 + mv.w);
    f0 = n0; f1 = n1; f2 = n2; f3 = n3;
    mv = mvn; st = stn; p = pn;
  }
  float* d = mats + ((long)chunk * T_NBATCH + b) * MAT_STRIDE + colslot * 4;
  float4 o; o.x = f0; o.y = f1; o.z = f2; o.w = f3;
  *(float4*)d = o;
}

// ---------- K2b: serial combine of chunk matrices per batch; logZ/T out ----------
__global__ void k_combine(const float* __restrict__ mats, float* __restrict__ logz,
                          int nchunks) {
  const int tid = threadIdx.x;       // 0..511
  const int i = tid & 3;             // state row
  const int b = tid >> 2;            // batch
  if (b >= T_NBATCH) return;
  float v = 0.0f;                    // v[i]; implicit v[4] = 0 constant

  const float* Tb = mats + (long)b * MAT_STRIDE;
  const long cstride = (long)T_NBATCH * MAT_STRIDE;
  // prefetch c=0 scalars
  float p0 = Tb[0 * 16 / 4 * 4];  // placeholder init below
  float q0 = Tb[i * 4 + i];
  float q1 = Tb[((i ^ 1) * 4) + i];
  float q2 = Tb[((i ^ 2) * 4) + i];
  float q3 = Tb[((i ^ 3) * 4) + i];
  float q4 = Tb[16 + i];
  (void)p0;
  for (int c = 0; c < nchunks; ++c) {
    const float* Tn = Tb + cstride;
    float n0 = 0, n1 = 0, n2 = 0, n3 = 0, n4 = 0;
    if (c + 1 < nchunks) {
      n0 = Tn[i * 4 + i];
      n1 = Tn[((i ^ 1) * 4) + i];
      n2 = Tn[((i ^ 2) * 4) + i];
      n3 = Tn[((i ^ 3) * 4) + i];
      n4 = Tn[16 + i];
    }
    const float vx1 = __shfl_xor(v, 1);
    const float vx2 = __shfl_xor(v, 2);
    const float vx3 = __shfl_xor(v, 3);
    const float a0 = q0 + v;
    const float a1 = q1 + vx1;
    const float a2 = q2 + vx2;
    const float a3 = q3 + vx3;
    const float a4 = q4;
    float m = fmaxf(fmaxf(a0, a1), fmaxf(fmaxf(a2, a3), a4));
    v = m + __logf(__expf(a0 - m) + __expf(a1 - m) + __expf(a2 - m) +
                   __expf(a3 - m) + __expf(a4 - m));
    q0 = n0; q1 = n1; q2 = n2; q3 = n3; q4 = n4;
    Tb = Tn;
  }
  float m1 = fmaxf(v, __shfl_xor(v, 1));
  m1 = fmaxf(m1, __shfl_xor(m1, 2));
  float e = __expf(v - m1);
  e += __shfl_xor(e, 1);
  e += __shfl_xor(e, 2);
  const float lz = m1 + __logf(e);
  if (i == 0) logz[b] = lz * (1.0f / (float)T_NTIME);
}

// ---------- K3: out[t][b][8..15] -= logZ[b]/T ----------
__global__ void k_sub(float* __restrict__ out, const float* __restrict__ logz) {
  const long n = (long)blockIdx.x * blockDim.x + threadIdx.x;
  if (n >= (long)T_NROWS * 2) return;
  const long tb = n >> 1;
  const int b = (int)(tb & (T_NBATCH - 1));
  const float lz = logz[b];
  float4* p = (float4*)(out + tb * T_SIZE + 8 + (n & 1) * 4);
  float4 v = *p;
  v.x -= lz; v.y -= lz; v.z -= lz; v.w -= lz;
  *p = v;
}

extern "C" void kernel_launch(void* const* d_in, const int* in_sizes, int n_in,
                              void* d_out, int out_size, void* d_ws, size_t ws_size,
                              hipStream_t stream) {
  const float* x    = (const float*)d_in[0];
  const float* W    = (const float*)d_in[1];
  const float* bias = (const float*)d_in[2];
  float* out = (float*)d_out;
  float* ws  = (float*)d_ws;

  int C = 64;
  while (C > 1 && (size_t)((long)C * T_NBATCH * MAT_STRIDE + T_NBATCH) * 4 > ws_size) C >>= 1;
  float* mats = ws;
  float* logz = ws + (long)C * T_NBATCH * MAT_STRIDE;

  k_gemm_act<<<T_NROWS / 256, 256, 0, stream>>>(x, W, bias, out);

  const int thr2 = C * T_NBATCH * 8;
  k_scan_chunks<<<thr2 / 256, 256, 0, stream>>>(out, mats, C);
  k_combine<<<1, 512, 0, stream>>>(mats, logz, C);
  k_sub<<<(T_NROWS * 2) / 256, 256, 0, stream>>>(out, logz);
}

// Round 4
// 281.131 us; speedup vs baseline: 4.0720x; 1.4543x over previous
//
#include <hip/hip_runtime.h>
#include <math.h>

#define T_NTIME  2048
#define T_NBATCH 128
#define T_INSIZE 512
#define T_SIZE   16
#define T_NROWS  (T_NTIME * T_NBATCH)
#define MAT_STRIDE 24   // padded per-(chunk,b) transfer-matrix stride (floats)

__device__ __forceinline__ float sp_f(float v) {
  return fmaxf(v, 0.0f) + log1pf(__expf(-fabsf(v)));
}
__device__ __forceinline__ float tanh5_f(float v) {
  float a = fabsf(v);
  float e = __expf(-2.0f * a);
  float t = (1.0f - e) / (1.0f + e);
  return copysignf(5.0f * t, v);
}
__device__ __forceinline__ float lae_f(float a, float c) {
  float m = fmaxf(a, c);
  return m + log1pf(__expf(-fabsf(a - c)));
}

// ---------- K1: y = x @ W^T + b, activations; trans written pre-logZ ----------
// One row per thread, streamed in 32 groups of 64B (4 x float4), ping-pong
// register prefetch sized to stay under 64 VGPRs (no scratch spill).
// W broadcast from LDS (uniform-address ds_read_b128, conflict-free).
__global__ __launch_bounds__(256, 4)
void k_gemm_act(const float* __restrict__ x, const float* __restrict__ W,
                const float* __restrict__ bias, float* __restrict__ out) {
  __shared__ float wl[T_SIZE * T_INSIZE];  // 32 KB
  const int tid = threadIdx.x;
  {
    const float4* src = (const float4*)W;
    float4* dst = (float4*)wl;
#pragma unroll
    for (int k = 0; k < 8; ++k) dst[tid + k * 256] = src[tid + k * 256];
  }
  __syncthreads();

  const long row = (long)blockIdx.x * 256 + tid;
  const float* __restrict__ xp = x + row * T_INSIZE;

  float acc[T_SIZE];
#pragma unroll
  for (int s = 0; s < T_SIZE; ++s) acc[s] = 0.0f;

  float4 cur[4], nxt[4];
#pragma unroll
  for (int j = 0; j < 4; ++j) cur[j] = *(const float4*)(xp + j * 4);

#define COMPUTE_GROUP(buf, gg)                                                   \
  do {                                                                           \
    _Pragma("unroll")                                                            \
    for (int j = 0; j < 4; ++j) {                                                \
      const float4 xv = buf[j];                                                  \
      _Pragma("unroll")                                                          \
      for (int s = 0; s < T_SIZE; ++s) {                                         \
        const float4 w4 = *(const float4*)(wl + s * T_INSIZE + (gg) * 16 + j * 4); \
        acc[s] = fmaf(xv.x, w4.x, acc[s]);                                       \
        acc[s] = fmaf(xv.y, w4.y, acc[s]);                                       \
        acc[s] = fmaf(xv.z, w4.z, acc[s]);                                       \
        acc[s] = fmaf(xv.w, w4.w, acc[s]);                                       \
      }                                                                          \
    }                                                                            \
  } while (0)

#pragma unroll 1
  for (int g = 0; g < 32; g += 2) {
#pragma unroll
    for (int j = 0; j < 4; ++j) nxt[j] = *(const float4*)(xp + (g + 1) * 16 + j * 4);
    COMPUTE_GROUP(cur, g);
    if (g + 2 < 32) {
#pragma unroll
      for (int j = 0; j < 4; ++j) cur[j] = *(const float4*)(xp + (g + 2) * 16 + j * 4);
    }
    COMPUTE_GROUP(nxt, g + 1);
  }
#undef COMPUTE_GROUP

  float* op = out + row * T_SIZE;
  float4 v;
  v.x = 1.0f + sp_f(acc[0] + bias[0]);
  v.y = 1.0f + sp_f(acc[1] + bias[1]);
  v.z = 1.0f + sp_f(acc[2] + bias[2]);
  v.w = 1.0f + sp_f(acc[3] + bias[3]);
  *(float4*)(op + 0) = v;
  v.x = 0.1f + sp_f(acc[4] + bias[4]);
  v.y = 0.1f + sp_f(acc[5] + bias[5]);
  v.z = 0.1f + sp_f(acc[6] + bias[6]);
  v.w = 0.1f + sp_f(acc[7] + bias[7]);
  *(float4*)(op + 4) = v;
  v.x = tanh5_f(acc[8] + bias[8]);
  v.y = tanh5_f(acc[9] + bias[9]);
  v.z = tanh5_f(acc[10] + bias[10]);
  v.w = tanh5_f(acc[11] + bias[11]);
  *(float4*)(op + 8) = v;
  v.x = tanh5_f(acc[12] + bias[12]);
  v.y = tanh5_f(acc[13] + bias[13]);
  v.z = tanh5_f(acc[14] + bias[14]);
  v.w = tanh5_f(acc[15] + bias[15]);
  *(float4*)(op + 12) = v;
}

// ---------- K2a: per-(b, chunk, basis-col) chunk transfer-matrix columns ----------
__global__ void k_scan_chunks(const float* __restrict__ out, float* __restrict__ mats,
                              int nchunks) {
  const int gtid = blockIdx.x * blockDim.x + threadIdx.x;
  const int colslot = gtid & 7;
  const int b = (gtid >> 3) & (T_NBATCH - 1);
  const int chunk = gtid >> 10;
  if (chunk >= nchunks) return;
  if (colslot >= 5) return;

  const int steps = T_NTIME / nchunks;
  const int t0 = chunk * steps;
  const float NEG = -1e30f;
  float f0 = (colslot == 0) ? 0.0f : NEG;
  float f1 = (colslot == 1) ? 0.0f : NEG;
  float f2 = (colslot == 2) ? 0.0f : NEG;
  float f3 = (colslot == 3) ? 0.0f : NEG;
  const float t4 = (colslot == 4) ? 0.0f : NEG;

  const long stride = T_NBATCH * T_SIZE;
  const float* p = out + ((long)t0 * T_NBATCH + b) * T_SIZE + 8;
  float4 mv = *(const float4*)(p);
  float4 st = *(const float4*)(p + 4);
  for (int s = 0; s < steps; ++s) {
    const float* pn = (s + 1 < steps) ? p + stride : p;
    const float4 mvn = *(const float4*)(pn);
    const float4 stn = *(const float4*)(pn + 4);

    float m, ss0, ss1, ss2, ss3;
    m = fmaxf(fmaxf(f1, f2), fmaxf(f3, t4));
    ss0 = m + __logf(__expf(f1 - m) + __expf(f2 - m) + __expf(f3 - m) + __expf(t4 - m));
    m = fmaxf(fmaxf(f0, f2), fmaxf(f3, t4));
    ss1 = m + __logf(__expf(f0 - m) + __expf(f2 - m) + __expf(f3 - m) + __expf(t4 - m));
    m = fmaxf(fmaxf(f0, f1), fmaxf(f3, t4));
    ss2 = m + __logf(__expf(f0 - m) + __expf(f1 - m) + __expf(f3 - m) + __expf(t4 - m));
    m = fmaxf(fmaxf(f0, f1), fmaxf(f2, t4));
    ss3 = m + __logf(__expf(f0 - m) + __expf(f1 - m) + __expf(f2 - m) + __expf(t4 - m));

    const float n0 = lae_f(f0 + st.x, ss0 + mv.x);
    const float n1 = lae_f(f1 + st.y, ss1 + mv.y);
    const float n2 = lae_f(f2 + st.z, ss2 + mv.z);
    const float n3 = lae_f(f3 + st.w, ss3 + mv.w);
    f0 = n0; f1 = n1; f2 = n2; f3 = n3;
    mv = mvn; st = stn; p = pn;
  }
  float* d = mats + ((long)chunk * T_NBATCH + b) * MAT_STRIDE + colslot * 4;
  float4 o; o.x = f0; o.y = f1; o.z = f2; o.w = f3;
  *(float4*)d = o;
}

// ---------- K2b: serial combine of chunk matrices per batch; logZ/T out ----------
__global__ void k_combine(const float* __restrict__ mats, float* __restrict__ logz,
                          int nchunks) {
  const int tid = threadIdx.x;       // 0..511
  const int i = tid & 3;             // state row
  const int b = tid >> 2;            // batch
  if (b >= T_NBATCH) return;
  float v = 0.0f;                    // v[i]; implicit v[4] = 0 constant

  const float* Tb = mats + (long)b * MAT_STRIDE;
  const long cstride = (long)T_NBATCH * MAT_STRIDE;
  float q0 = Tb[i * 4 + i];
  float q1 = Tb[((i ^ 1) * 4) + i];
  float q2 = Tb[((i ^ 2) * 4) + i];
  float q3 = Tb[((i ^ 3) * 4) + i];
  float q4 = Tb[16 + i];
  for (int c = 0; c < nchunks; ++c) {
    const float* Tn = Tb + cstride;
    float n0 = 0, n1 = 0, n2 = 0, n3 = 0, n4 = 0;
    if (c + 1 < nchunks) {
      n0 = Tn[i * 4 + i];
      n1 = Tn[((i ^ 1) * 4) + i];
      n2 = Tn[((i ^ 2) * 4) + i];
      n3 = Tn[((i ^ 3) * 4) + i];
      n4 = Tn[16 + i];
    }
    const float vx1 = __shfl_xor(v, 1);
    const float vx2 = __shfl_xor(v, 2);
    const float vx3 = __shfl_xor(v, 3);
    const float a0 = q0 + v;
    const float a1 = q1 + vx1;
    const float a2 = q2 + vx2;
    const float a3 = q3 + vx3;
    const float a4 = q4;
    float m = fmaxf(fmaxf(a0, a1), fmaxf(fmaxf(a2, a3), a4));
    v = m + __logf(__expf(a0 - m) + __expf(a1 - m) + __expf(a2 - m) +
                   __expf(a3 - m) + __expf(a4 - m));
    q0 = n0; q1 = n1; q2 = n2; q3 = n3; q4 = n4;
    Tb = Tn;
  }
  float m1 = fmaxf(v, __shfl_xor(v, 1));
  m1 = fmaxf(m1, __shfl_xor(m1, 2));
  float e = __expf(v - m1);
  e += __shfl_xor(e, 1);
  e += __shfl_xor(e, 2);
  const float lz = m1 + __logf(e);
  if (i == 0) logz[b] = lz * (1.0f / (float)T_NTIME);
}

// ---------- K3: out[t][b][8..15] -= logZ[b]/T ----------
__global__ void k_sub(float* __restrict__ out, const float* __restrict__ logz) {
  const long n = (long)blockIdx.x * blockDim.x + threadIdx.x;
  if (n >= (long)T_NROWS * 2) return;
  const long tb = n >> 1;
  const int b = (int)(tb & (T_NBATCH - 1));
  const float lz = logz[b];
  float4* p = (float4*)(out + tb * T_SIZE + 8 + (n & 1) * 4);
  float4 v = *p;
  v.x -= lz; v.y -= lz; v.z -= lz; v.w -= lz;
  *p = v;
}

extern "C" void kernel_launch(void* const* d_in, const int* in_sizes, int n_in,
                              void* d_out, int out_size, void* d_ws, size_t ws_size,
                              hipStream_t stream) {
  const float* x    = (const float*)d_in[0];
  const float* W    = (const float*)d_in[1];
  const float* bias = (const float*)d_in[2];
  float* out = (float*)d_out;
  float* ws  = (float*)d_ws;

  int C = 64;
  while (C > 1 && (size_t)((long)C * T_NBATCH * MAT_STRIDE + T_NBATCH) * 4 > ws_size) C >>= 1;
  float* mats = ws;
  float* logz = ws + (long)C * T_NBATCH * MAT_STRIDE;

  k_gemm_act<<<T_NROWS / 256, 256, 0, stream>>>(x, W, bias, out);

  const int thr2 = C * T_NBATCH * 8;
  k_scan_chunks<<<thr2 / 256, 256, 0, stream>>>(out, mats, C);
  k_combine<<<1, 512, 0, stream>>>(mats, logz, C);
  k_sub<<<(T_NROWS * 2) / 256, 256, 0, stream>>>(out, logz);
}

// Round 5
// 259.109 us; speedup vs baseline: 4.4181x; 1.0850x over previous
//
#include <hip/hip_runtime.h>
#include <math.h>

#define T_NTIME  2048
#define T_NBATCH 128
#define T_INSIZE 512
#define T_SIZE   16
#define T_NROWS  (T_NTIME * T_NBATCH)
#define MAT_STRIDE 24   // padded per-(chunk,b) transfer-matrix stride (floats)

__device__ __forceinline__ float sp_f(float v) {
  return fmaxf(v, 0.0f) + log1pf(__expf(-fabsf(v)));
}
__device__ __forceinline__ float tanh5_f(float v) {
  float a = fabsf(v);
  float e = __expf(-2.0f * a);
  float t = (1.0f - e) / (1.0f + e);
  return copysignf(5.0f * t, v);
}
__device__ __forceinline__ float lae_f(float a, float c) {
  float m = fmaxf(a, c);
  return m + log1pf(__expf(-fabsf(a - c)));
}

__device__ __forceinline__ void emit_row(float* op, const float (&acc)[T_SIZE],
                                         const float* __restrict__ bias) {
  float4 v;
  v.x = 1.0f + sp_f(acc[0] + bias[0]);
  v.y = 1.0f + sp_f(acc[1] + bias[1]);
  v.z = 1.0f + sp_f(acc[2] + bias[2]);
  v.w = 1.0f + sp_f(acc[3] + bias[3]);
  *(float4*)(op + 0) = v;
  v.x = 0.1f + sp_f(acc[4] + bias[4]);
  v.y = 0.1f + sp_f(acc[5] + bias[5]);
  v.z = 0.1f + sp_f(acc[6] + bias[6]);
  v.w = 0.1f + sp_f(acc[7] + bias[7]);
  *(float4*)(op + 4) = v;
  v.x = tanh5_f(acc[8] + bias[8]);
  v.y = tanh5_f(acc[9] + bias[9]);
  v.z = tanh5_f(acc[10] + bias[10]);
  v.w = tanh5_f(acc[11] + bias[11]);
  *(float4*)(op + 8) = v;
  v.x = tanh5_f(acc[12] + bias[12]);
  v.y = tanh5_f(acc[13] + bias[13]);
  v.z = tanh5_f(acc[14] + bias[14]);
  *(float4*)(op + 12) = v;
  // careful: compute w before store (kept separate to avoid aliasing surprises)
  ((float*)(op + 12))[3] = tanh5_f(acc[15] + bias[15]);
}

// ---------- K1: y = x @ W^T + b, activations; trans written pre-logZ ----------
// TWO rows per thread: each uniform W ds_read_b128 is reused for both rows,
// halving LDS-pipe instructions per row (the R4 limiter: 2048 ds_read/row-wave
// ~= 12cy each -> 164us/CU; now ~82us, under the ~90us HBM floor).
// Row stream: 32 groups of 64B (4 x float4) per row, ping-pong prefetch.
__global__ __launch_bounds__(256, 2)
void k_gemm_act(const float* __restrict__ x, const float* __restrict__ W,
                const float* __restrict__ bias, float* __restrict__ out) {
  __shared__ float wl[T_SIZE * T_INSIZE];  // 32 KB
  const int tid = threadIdx.x;
  {
    const float4* src = (const float4*)W;
    float4* dst = (float4*)wl;
#pragma unroll
    for (int k = 0; k < 8; ++k) dst[tid + k * 256] = src[tid + k * 256];
  }
  __syncthreads();

  const long row0 = (long)blockIdx.x * 512 + tid;   // and row0 + 256
  const float* __restrict__ xp0 = x + row0 * T_INSIZE;
  const float* __restrict__ xp1 = xp0 + 256L * T_INSIZE;

  float acc0[T_SIZE], acc1[T_SIZE];
#pragma unroll
  for (int s = 0; s < T_SIZE; ++s) { acc0[s] = 0.0f; acc1[s] = 0.0f; }

  float4 curA[4], curB[4], nxtA[4], nxtB[4];
#pragma unroll
  for (int j = 0; j < 4; ++j) {
    curA[j] = *(const float4*)(xp0 + j * 4);
    curB[j] = *(const float4*)(xp1 + j * 4);
  }

#define COMPUTE_GROUP(bufA, bufB, gg)                                            \
  do {                                                                           \
    _Pragma("unroll")                                                            \
    for (int j = 0; j < 4; ++j) {                                                \
      const float4 xa = bufA[j];                                                 \
      const float4 xb = bufB[j];                                                 \
      _Pragma("unroll")                                                          \
      for (int s = 0; s < T_SIZE; ++s) {                                         \
        const float4 w4 = *(const float4*)(wl + s * T_INSIZE + (gg) * 16 + j * 4); \
        acc0[s] = fmaf(xa.x, w4.x, acc0[s]);                                     \
        acc0[s] = fmaf(xa.y, w4.y, acc0[s]);                                     \
        acc0[s] = fmaf(xa.z, w4.z, acc0[s]);                                     \
        acc0[s] = fmaf(xa.w, w4.w, acc0[s]);                                     \
        acc1[s] = fmaf(xb.x, w4.x, acc1[s]);                                     \
        acc1[s] = fmaf(xb.y, w4.y, acc1[s]);                                     \
        acc1[s] = fmaf(xb.z, w4.z, acc1[s]);                                     \
        acc1[s] = fmaf(xb.w, w4.w, acc1[s]);                                     \
      }                                                                          \
    }                                                                            \
  } while (0)

#pragma unroll 1
  for (int g = 0; g < 32; g += 2) {
#pragma unroll
    for (int j = 0; j < 4; ++j) {
      nxtA[j] = *(const float4*)(xp0 + (g + 1) * 16 + j * 4);
      nxtB[j] = *(const float4*)(xp1 + (g + 1) * 16 + j * 4);
    }
    COMPUTE_GROUP(curA, curB, g);
    if (g + 2 < 32) {
#pragma unroll
      for (int j = 0; j < 4; ++j) {
        curA[j] = *(const float4*)(xp0 + (g + 2) * 16 + j * 4);
        curB[j] = *(const float4*)(xp1 + (g + 2) * 16 + j * 4);
      }
    }
    COMPUTE_GROUP(nxtA, nxtB, g + 1);
  }
#undef COMPUTE_GROUP

  emit_row(out + row0 * T_SIZE, acc0, bias);
  emit_row(out + (row0 + 256L) * T_SIZE, acc1, bias);
}

// ---------- K2a: per-(b, chunk, basis-col) chunk transfer-matrix columns ----------
__global__ void k_scan_chunks(const float* __restrict__ out, float* __restrict__ mats,
                              int nchunks) {
  const int gtid = blockIdx.x * blockDim.x + threadIdx.x;
  const int colslot = gtid & 7;
  const int b = (gtid >> 3) & (T_NBATCH - 1);
  const int chunk = gtid >> 10;
  if (chunk >= nchunks) return;
  if (colslot >= 5) return;

  const int steps = T_NTIME / nchunks;
  const int t0 = chunk * steps;
  const float NEG = -1e30f;
  float f0 = (colslot == 0) ? 0.0f : NEG;
  float f1 = (colslot == 1) ? 0.0f : NEG;
  float f2 = (colslot == 2) ? 0.0f : NEG;
  float f3 = (colslot == 3) ? 0.0f : NEG;
  const float t4 = (colslot == 4) ? 0.0f : NEG;

  const long stride = T_NBATCH * T_SIZE;
  const float* p = out + ((long)t0 * T_NBATCH + b) * T_SIZE + 8;
  float4 mv = *(const float4*)(p);
  float4 st = *(const float4*)(p + 4);
  for (int s = 0; s < steps; ++s) {
    const float* pn = (s + 1 < steps) ? p + stride : p;
    const float4 mvn = *(const float4*)(pn);
    const float4 stn = *(const float4*)(pn + 4);

    float m, ss0, ss1, ss2, ss3;
    m = fmaxf(fmaxf(f1, f2), fmaxf(f3, t4));
    ss0 = m + __logf(__expf(f1 - m) + __expf(f2 - m) + __expf(f3 - m) + __expf(t4 - m));
    m = fmaxf(fmaxf(f0, f2), fmaxf(f3, t4));
    ss1 = m + __logf(__expf(f0 - m) + __expf(f2 - m) + __expf(f3 - m) + __expf(t4 - m));
    m = fmaxf(fmaxf(f0, f1), fmaxf(f3, t4));
    ss2 = m + __logf(__expf(f0 - m) + __expf(f1 - m) + __expf(f3 - m) + __expf(t4 - m));
    m = fmaxf(fmaxf(f0, f1), fmaxf(f2, t4));
    ss3 = m + __logf(__expf(f0 - m) + __expf(f1 - m) + __expf(f2 - m) + __expf(t4 - m));

    const float n0 = lae_f(f0 + st.x, ss0 + mv.x);
    const float n1 = lae_f(f1 + st.y, ss1 + mv.y);
    const float n2 = lae_f(f2 + st.z, ss2 + mv.z);
    const float n3 = lae_f(f3 + st.w, ss3 + mv.w);
    f0 = n0; f1 = n1; f2 = n2; f3 = n3;
    mv = mvn; st = stn; p = pn;
  }
  float* d = mats + ((long)chunk * T_NBATCH + b) * MAT_STRIDE + colslot * 4;
  float4 o; o.x = f0; o.y = f1; o.z = f2; o.w = f3;
  *(float4*)d = o;
}

// ---------- K2b: serial combine of chunk matrices per batch; logZ/T out ----------
__global__ void k_combine(const float* __restrict__ mats, float* __restrict__ logz,
                          int nchunks) {
  const int tid = threadIdx.x;       // 0..511
  const int i = tid & 3;             // state row
  const int b = tid >> 2;            // batch
  if (b >= T_NBATCH) return;
  float v = 0.0f;                    // v[i]; implicit v[4] = 0 constant

  const float* Tb = mats + (long)b * MAT_STRIDE;
  const long cstride = (long)T_NBATCH * MAT_STRIDE;
  float q0 = Tb[i * 4 + i];
  float q1 = Tb[((i ^ 1) * 4) + i];
  float q2 = Tb[((i ^ 2) * 4) + i];
  float q3 = Tb[((i ^ 3) * 4) + i];
  float q4 = Tb[16 + i];
  for (int c = 0; c < nchunks; ++c) {
    const float* Tn = Tb + cstride;
    float n0 = 0, n1 = 0, n2 = 0, n3 = 0, n4 = 0;
    if (c + 1 < nchunks) {
      n0 = Tn[i * 4 + i];
      n1 = Tn[((i ^ 1) * 4) + i];
      n2 = Tn[((i ^ 2) * 4) + i];
      n3 = Tn[((i ^ 3) * 4) + i];
      n4 = Tn[16 + i];
    }
    const float vx1 = __shfl_xor(v, 1);
    const float vx2 = __shfl_xor(v, 2);
    const float vx3 = __shfl_xor(v, 3);
    const float a0 = q0 + v;
    const float a1 = q1 + vx1;
    const float a2 = q2 + vx2;
    const float a3 = q3 + vx3;
    const float a4 = q4;
    float m = fmaxf(fmaxf(a0, a1), fmaxf(fmaxf(a2, a3), a4));
    v = m + __logf(__expf(a0 - m) + __expf(a1 - m) + __expf(a2 - m) +
                   __expf(a3 - m) + __expf(a4 - m));
    q0 = n0; q1 = n1; q2 = n2; q3 = n3; q4 = n4;
    Tb = Tn;
  }
  float m1 = fmaxf(v, __shfl_xor(v, 1));
  m1 = fmaxf(m1, __shfl_xor(m1, 2));
  float e = __expf(v - m1);
  e += __shfl_xor(e, 1);
  e += __shfl_xor(e, 2);
  const float lz = m1 + __logf(e);
  if (i == 0) logz[b] = lz * (1.0f / (float)T_NTIME);
}

// ---------- K3: out[t][b][8..15] -= logZ[b]/T ----------
__global__ void k_sub(float* __restrict__ out, const float* __restrict__ logz) {
  const long n = (long)blockIdx.x * blockDim.x + threadIdx.x;
  if (n >= (long)T_NROWS * 2) return;
  const long tb = n >> 1;
  const int b = (int)(tb & (T_NBATCH - 1));
  const float lz = logz[b];
  float4* p = (float4*)(out + tb * T_SIZE + 8 + (n & 1) * 4);
  float4 v = *p;
  v.x -= lz; v.y -= lz; v.z -= lz; v.w -= lz;
  *p = v;
}

extern "C" void kernel_launch(void* const* d_in, const int* in_sizes, int n_in,
                              void* d_out, int out_size, void* d_ws, size_t ws_size,
                              hipStream_t stream) {
  const float* x    = (const float*)d_in[0];
  const float* W    = (const float*)d_in[1];
  const float* bias = (const float*)d_in[2];
  float* out = (float*)d_out;
  float* ws  = (float*)d_ws;

  int C = 64;
  while (C > 1 && (size_t)((long)C * T_NBATCH * MAT_STRIDE + T_NBATCH) * 4 > ws_size) C >>= 1;
  float* mats = ws;
  float* logz = ws + (long)C * T_NBATCH * MAT_STRIDE;

  k_gemm_act<<<T_NROWS / 512, 256, 0, stream>>>(x, W, bias, out);

  const int thr2 = C * T_NBATCH * 8;
  k_scan_chunks<<<thr2 / 256, 256, 0, stream>>>(out, mats, C);
  k_combine<<<1, 512, 0, stream>>>(mats, logz, C);
  k_sub<<<(T_NROWS * 2) / 256, 256, 0, stream>>>(out, logz);
}